// Round 8
// baseline (372.193 us; speedup 1.0000x reference)
//
#include <hip/hip_runtime.h>

namespace {

typedef __attribute__((ext_vector_type(8))) short bf16x8;
typedef __attribute__((ext_vector_type(4))) float f32x4;

constexpr int C     = 128;
constexpr int HF    = 116;
constexpr int WF    = 200;
constexpr int PTILE = 32;
constexpr int BLK   = 256;
constexpr int NPTS  = 200000;
constexpr int AS_STRIDE  = 264;   // 256 + 8 shorts pad
constexpr int HID_STRIDE = 136;   // (prep LDS transpose stride)

// ws layout (short offsets): packed bf16 weights in B-frag order
constexpr int W_LE1 = 0;          // 256x128 -> 32768 shorts
constexpr int W_LE2 = 32768;      // 128x128 -> 16384
constexpr int W_FG  = 49152;      // 128x64  -> 8192
constexpr int W_RT  = 57344;      // 128x64  -> 8192 (rows 0..127 of rt_w1)
constexpr size_t IMG_BYTE_OFF = 131072;   // NHWC bf16 image, 23.76 MB

constexpr int IMG_BLOCKS = 4 * HF * 2;    // 928 half-row transpose blocks
constexpr int WP_BLOCKS  = 256;           // weight pack blocks

__device__ __forceinline__ float b2f(unsigned short u) {
  union { unsigned int i; float f; } v; v.i = ((unsigned int)u) << 16; return v.f;
}
__device__ __forceinline__ unsigned short f2b(float f) {
  union { float f; unsigned int i; } v; v.f = f;
  unsigned int i = v.i;
  return (unsigned short)((i + 0x7fffu + ((i >> 16) & 1u)) >> 16);
}
__device__ __forceinline__ void unp(unsigned int u, float& lo, float& hi) {
  union { unsigned int i; float f; } a, b;
  a.i = u << 16; b.i = u & 0xffff0000u; lo = a.f; hi = b.f;
}
// packed f32x2 -> bf16x2 (RNE), single HW instruction
__device__ __forceinline__ unsigned int packb(float a, float b) {
  unsigned int r;
  asm("v_cvt_pk_bf16_f32 %0, %1, %2" : "=v"(r) : "v"(a), "v"(b));
  return r;
}

// ---- fused prep: image NCHW f32 -> NHWC bf16 (vectorized) + weight pack ----
__global__ __launch_bounds__(BLK) void prep_kernel(
    const float* __restrict__ imgf,
    const float* __restrict__ le_w1, const float* __restrict__ le_w2,
    const float* __restrict__ fg_w1, const float* __restrict__ rt_w1,
    short* __restrict__ wpack, short* __restrict__ imgT) {
  __shared__ short buf[100 * HID_STRIDE];   // [x][c], 27.2 KB
  const int blk = blockIdx.x;
  if (blk < IMG_BLOCKS) {
    const int half = blk & 1, by = blk >> 1;
    const int b = by / HF, y = by - b * HF;
    const int x0 = half * 100;
    const float* s = imgf + (size_t)b * C * HF * WF + (size_t)y * WF + x0;
    for (int i = threadIdx.x; i < C * 25; i += BLK) {
      int c = i / 25, qx = i - c * 25;
      float4 v = *(const float4*)(s + (size_t)c * (HF * WF) + qx * 4);
      int xb = qx * 4;
      buf[(xb + 0) * HID_STRIDE + c] = (short)f2b(v.x);
      buf[(xb + 1) * HID_STRIDE + c] = (short)f2b(v.y);
      buf[(xb + 2) * HID_STRIDE + c] = (short)f2b(v.z);
      buf[(xb + 3) * HID_STRIDE + c] = (short)f2b(v.w);
    }
    __syncthreads();
    short* d = imgT + ((size_t)(b * HF + y) * WF + x0) * C;
    for (int i = threadIdx.x; i < 100 * 16; i += BLK) {
      int xx = i >> 4, c8 = (i & 15) << 3;
      *(uint4*)(d + (size_t)xx * C + c8) = *(const uint4*)&buf[xx * HID_STRIDE + c8];
    }
  } else {
    int idx = (blk - IMG_BLOCKS) * BLK + threadIdx.x;   // 0..65535
    if (idx < 32768) {                     // le_w1 (256,128)
      int k = idx >> 7, n = idx & 127;
      wpack[W_LE1 + (((k >> 3) * 128 + n) << 3) + (k & 7)] = (short)f2b(le_w1[idx]);
    } else if (idx < 49152) {              // le_w2 (128,128)
      int l = idx - 32768; int k = l >> 7, n = l & 127;
      wpack[W_LE2 + (((k >> 3) * 128 + n) << 3) + (k & 7)] = (short)f2b(le_w2[l]);
    } else if (idx < 57344) {              // fg_w1 (128,64)
      int l = idx - 49152; int k = l >> 6, n = l & 63;
      wpack[W_FG + (((k >> 3) * 64 + n) << 3) + (k & 7)] = (short)f2b(fg_w1[l]);
    } else {                               // rt_w1 rows 0..127 (of 131,64)
      int l = idx - 57344; int k = l >> 6, n = l & 63;
      wpack[W_RT + (((k >> 3) * 64 + n) << 3) + (k & 7)] = (short)f2b(rt_w1[k * 64 + n]);
    }
  }
}

// ---- main fused kernel ----
// R5 base + B-fragment dedup in le1/le2: each wave owns a DISTINCT 32-col
// slice x all 32 rows (acc[2][2] = 16 VGPR, spill-safe). Per-block le1 B-reads
// 128->64KB, le2 64->32KB. LN is a 4-way partial combine via s_lnpart[4][32].
__global__ __launch_bounds__(BLK, 6) void fuse_kernel(
    const float* __restrict__ x,       // (N,128)
    const int*   __restrict__ indices, // (N,4)
    const float* __restrict__ vox, const float* __restrict__ pcr,
    const float* __restrict__ trans,
    const int* __restrict__ imgh_p, const int* __restrict__ imgw_p,
    const float* __restrict__ fg_b1v, const float* __restrict__ fg_w2v,
    const float* __restrict__ fg_b2v,
    const float* __restrict__ rt_w1f,  // raw f32 (need rows 128..130)
    const float* __restrict__ rt_b1v, const float* __restrict__ rt_w2v,
    const float* __restrict__ rt_b2v,
    const float* __restrict__ le_b1v, const float* __restrict__ le_b2v,
    const float* __restrict__ ln_gv, const float* __restrict__ ln_bv,
    const short* __restrict__ wpack,   // packed bf16 weights (ws)
    const short* __restrict__ imgT,    // NHWC bf16 (ws)
    float* __restrict__ out_fused, float* __restrict__ out_qual) {
  __shared__ short As[PTILE * AS_STRIDE];     // [p][k]: x | sampled->hidden
  __shared__ float s_rn[32], s_pfg[32], s_valid[32], s_px[32], s_py[32];
  __shared__ float s_gain[32], s_rv[32];
  __shared__ float s_route[32][3];
  __shared__ int   s_bat[32];
  __shared__ __align__(16) float s_lnpart[4][32][4];   // [wave][row][4 stats]

  const int tid  = threadIdx.x;
  const int n0   = blockIdx.x * PTILE;
  const int wave = tid >> 6;
  const int lane = tid & 63;
  const int q    = lane >> 4;     // quad
  const int nn   = lane & 15;

  // ================= P0: stage x -> As bf16; geometry ==========
  {
    const float4* xsrc = (const float4*)(x + (size_t)n0 * C);
    for (int i = tid; i < PTILE * C / 4; i += BLK) {   // 1024 float4
      float4 v = xsrc[i];
      int p = i >> 5, c4 = (i & 31) * 4;
      uint2 sv = { packb(v.x, v.y), packb(v.z, v.w) };
      *(uint2*)&As[p * AS_STRIDE + c4] = sv;
    }
  }
  if (tid < PTILE) {
    int p = tid;
    int base = (n0 + p) * 4;
    int bi = indices[base + 0], zi = indices[base + 1];
    int yi = indices[base + 2], xi = indices[base + 3];
    float sp[3] = { (float)xi, (float)yi, (float)zi };
    float cen[3];
#pragma unroll
    for (int k = 0; k < 3; ++k) {
      float cvs = vox[k] * 8.0f;
      cen[k] = sp[k] * cvs + pcr[k] + cvs * 0.5f;
    }
    float rn = sqrtf(cen[0] * cen[0] + cen[1] * cen[1]) / 72.0f;
    rn = fminf(fmaxf(rn, 0.0f), 1.0f);
    float pt3[3];
#pragma unroll
    for (int r = 0; r < 3; ++r) {
      const float* row = trans + (bi * 3 + r) * 4;
      pt3[r] = row[0] * cen[0] + row[1] * cen[1] + row[2] * cen[2] + row[3];
    }
    float depth = pt3[2];
    float safe  = fmaxf(depth, 1e-5f);
    float uf = pt3[0] / safe * ((float)WF / (float)imgw_p[0]);
    float vf = pt3[1] / safe * ((float)HF / (float)imgh_p[0]);
    float un = 2.0f * (uf / (float)(WF - 1)) - 1.0f;
    float vn = 2.0f * (vf / (float)(HF - 1)) - 1.0f;
    bool valid = (depth > 1e-5f) && (fabsf(un) <= 1.0f) && (fabsf(vn) <= 1.0f);
    s_rn[p] = rn;
    s_valid[p] = valid ? 1.0f : 0.0f;
    s_bat[p] = bi;
    s_px[p] = (un + 1.0f) * 0.5f * (float)(WF - 1);
    s_py[p] = (vn + 1.0f) * 0.5f * (float)(HF - 1);
  }
  __syncthreads();

  // ================= P1: waves0,1 fg MFMA+epi ; waves2,3 rt x-part MFMA =======
  f32x4 accS[4];
#pragma unroll
  for (int t = 0; t < 4; ++t) accS[t] = (f32x4){0.f, 0.f, 0.f, 0.f};
  if (wave < 2) {
    const int p0 = wave * 16;
    const bf16x8* Bfg = (const bf16x8*)(wpack + W_FG);
#pragma unroll 2
    for (int ks = 0; ks < 4; ++ks) {
      bf16x8 a = *(const bf16x8*)&As[(p0 + nn) * AS_STRIDE + ks * 32 + q * 8];
#pragma unroll
      for (int t = 0; t < 4; ++t) {
        bf16x8 b = Bfg[(ks * 4 + q) * 64 + t * 16 + nn];
        accS[t] = __builtin_amdgcn_mfma_f32_16x16x32_bf16(a, b, accS[t], 0, 0, 0);
      }
    }
    float part[4] = {0.f, 0.f, 0.f, 0.f};
#pragma unroll
    for (int t = 0; t < 4; ++t) {
      int col = t * 16 + nn;
      float bias = fg_b1v[col];
      float wv2  = fg_w2v[col];
#pragma unroll
      for (int r = 0; r < 4; ++r)
        part[r] += fmaxf(accS[t][r] + bias, 0.f) * wv2;
    }
#pragma unroll
    for (int off = 1; off < 16; off <<= 1) {
#pragma unroll
      for (int r = 0; r < 4; ++r) part[r] += __shfl_xor(part[r], off);
    }
    if (nn == 0) {
      float b2 = fg_b2v[0];
#pragma unroll
      for (int r = 0; r < 4; ++r)
        s_pfg[p0 + q * 4 + r] = 1.f / (1.f + expf(-(part[r] + b2)));
    }
  } else {
    const int p0 = (wave - 2) * 16;
    const bf16x8* Brt = (const bf16x8*)(wpack + W_RT);
#pragma unroll 2
    for (int ks = 0; ks < 4; ++ks) {
      bf16x8 a = *(const bf16x8*)&As[(p0 + nn) * AS_STRIDE + ks * 32 + q * 8];
#pragma unroll
      for (int t = 0; t < 4; ++t) {
        bf16x8 b = Brt[(ks * 4 + q) * 64 + t * 16 + nn];
        accS[t] = __builtin_amdgcn_mfma_f32_16x16x32_bf16(a, b, accS[t], 0, 0, 0);
      }
    }
  }
  __syncthreads();

  // ====== P2: rt ext+epi (waves 2,3); sampling (all threads) ==================
  if (wave >= 2) {
    const int p0 = (wave - 2) * 16;
    float lg0[4] = {0,0,0,0}, lg1[4] = {0,0,0,0}, lg2[4] = {0,0,0,0};
#pragma unroll
    for (int t = 0; t < 4; ++t) {
      int col = t * 16 + nn;
      float b1 = rt_b1v[col];
      float wr = rt_w1f[128 * 64 + col];
      float wp = rt_w1f[129 * 64 + col];
      float wv = rt_w1f[130 * 64 + col];
      float w20 = rt_w2v[col * 3 + 0], w21 = rt_w2v[col * 3 + 1], w22 = rt_w2v[col * 3 + 2];
#pragma unroll
      for (int r = 0; r < 4; ++r) {
        int p = p0 + q * 4 + r;
        float h = accS[t][r] + b1 + s_rn[p] * wr + s_pfg[p] * wp + s_valid[p] * wv;
        h = fmaxf(h, 0.f);
        lg0[r] += h * w20; lg1[r] += h * w21; lg2[r] += h * w22;
      }
    }
#pragma unroll
    for (int off = 1; off < 16; off <<= 1) {
#pragma unroll
      for (int r = 0; r < 4; ++r) {
        lg0[r] += __shfl_xor(lg0[r], off);
        lg1[r] += __shfl_xor(lg1[r], off);
        lg2[r] += __shfl_xor(lg2[r], off);
      }
    }
    if (nn == 0) {
      float rb0 = rt_b2v[0], rb1 = rt_b2v[1], rb2 = rt_b2v[2];
#pragma unroll
      for (int r = 0; r < 4; ++r) {
        int p = p0 + q * 4 + r;
        float l0 = lg0[r] + rb0, l1 = lg1[r] + rb1, l2 = lg2[r] + rb2;
        float m = fmaxf(l0, fmaxf(l1, l2));
        float e0 = expf(l0 - m), e1 = expf(l1 - m), e2 = expf(l2 - m);
        float inv = 1.f / (e0 + e1 + e2);
        s_route[p][0] = e0 * inv; s_route[p][1] = e1 * inv; s_route[p][2] = e2 * inv;
        s_rv[p] = e1 * inv * s_valid[p];
      }
    }
  }
  // sampling (all threads): thread = (point, 16-ch group)
  {
    int p = tid >> 3, grp = tid & 7, ch0 = grp * 16;
    float sacc[16];
#pragma unroll
    for (int k = 0; k < 16; ++k) sacc[k] = 0.f;
    if (s_valid[p] > 0.5f) {
      float px = s_px[p], py = s_py[p];
      float x0f = floorf(px), y0f = floorf(py);
      float fx = px - x0f, fy = py - y0f;
      int ix = (int)x0f, iy = (int)y0f;
      int bb = s_bat[p];
#pragma unroll
      for (int dy = 0; dy < 2; ++dy) {
#pragma unroll
        for (int dx = 0; dx < 2; ++dx) {
          int xi = ix + dx, yi = iy + dy;
          if (xi >= 0 && xi < WF && yi >= 0 && yi < HF) {
            float w = (dx ? fx : 1.0f - fx) * (dy ? fy : 1.0f - fy);
            const short* tp = imgT + (((size_t)bb * HF + yi) * WF + xi) * C + ch0;
            uint4 u0 = *(const uint4*)tp;
            uint4 u1 = *(const uint4*)(tp + 8);
            float lo, hi;
            unp(u0.x, lo, hi); sacc[0] += w * lo;  sacc[1] += w * hi;
            unp(u0.y, lo, hi); sacc[2] += w * lo;  sacc[3] += w * hi;
            unp(u0.z, lo, hi); sacc[4] += w * lo;  sacc[5] += w * hi;
            unp(u0.w, lo, hi); sacc[6] += w * lo;  sacc[7] += w * hi;
            unp(u1.x, lo, hi); sacc[8] += w * lo;  sacc[9] += w * hi;
            unp(u1.y, lo, hi); sacc[10] += w * lo; sacc[11] += w * hi;
            unp(u1.z, lo, hi); sacc[12] += w * lo; sacc[13] += w * hi;
            unp(u1.w, lo, hi); sacc[14] += w * lo; sacc[15] += w * hi;
          }
        }
      }
    }
    uint4 o0 = { packb(sacc[0], sacc[1]),  packb(sacc[2], sacc[3]),
                 packb(sacc[4], sacc[5]),  packb(sacc[6], sacc[7]) };
    uint4 o1 = { packb(sacc[8], sacc[9]),  packb(sacc[10], sacc[11]),
                 packb(sacc[12], sacc[13]), packb(sacc[14], sacc[15]) };
    *(uint4*)&As[p * AS_STRIDE + 128 + ch0]     = o0;
    *(uint4*)&As[p * AS_STRIDE + 128 + ch0 + 8] = o1;
  }
  __syncthreads();

  // ====== P3: le1 MFMA K=256. Wave owns cols [wave*32, wave*32+32) x 32 rows ==
  {
    const bf16x8* Ble1 = (const bf16x8*)(wpack + W_LE1);
    f32x4 acc[2][2];   // [rg][t2], 16 VGPR
#pragma unroll
    for (int rg = 0; rg < 2; ++rg)
#pragma unroll
      for (int t2 = 0; t2 < 2; ++t2) acc[rg][t2] = (f32x4){0.f, 0.f, 0.f, 0.f};
#pragma unroll 2
    for (int ks = 0; ks < 8; ++ks) {
      bf16x8 b0 = Ble1[(ks * 4 + q) * 128 + (wave * 2 + 0) * 16 + nn];
      bf16x8 b1 = Ble1[(ks * 4 + q) * 128 + (wave * 2 + 1) * 16 + nn];
#pragma unroll
      for (int rg = 0; rg < 2; ++rg) {
        bf16x8 a = *(const bf16x8*)&As[(rg * 16 + nn) * AS_STRIDE + ks * 32 + q * 8];
        acc[rg][0] = __builtin_amdgcn_mfma_f32_16x16x32_bf16(a, b0, acc[rg][0], 0, 0, 0);
        acc[rg][1] = __builtin_amdgcn_mfma_f32_16x16x32_bf16(a, b1, acc[rg][1], 0, 0, 0);
      }
    }
    // all waves done READING As[*][128..255]; overwrite with hidden bf16
    __syncthreads();
#pragma unroll
    for (int t2 = 0; t2 < 2; ++t2) {
      int col = (wave * 2 + t2) * 16 + nn;
      float bias = le_b1v[col];
#pragma unroll
      for (int rg = 0; rg < 2; ++rg)
#pragma unroll
        for (int r = 0; r < 4; ++r)
          As[(rg * 16 + q * 4 + r) * AS_STRIDE + 128 + col] =
              (short)f2b(fmaxf(acc[rg][t2][r] + bias, 0.f));
    }
    __syncthreads();
  }

  // ====== P5: le2 MFMA (same col-ownership) + delta/gain/4-way layernorm ======
  const bf16x8* Ble2 = (const bf16x8*)(wpack + W_LE2);
  f32x4 acc2[2][2];
#pragma unroll
  for (int rg = 0; rg < 2; ++rg)
#pragma unroll
    for (int t2 = 0; t2 < 2; ++t2) acc2[rg][t2] = (f32x4){0.f, 0.f, 0.f, 0.f};
#pragma unroll 2
  for (int ks = 0; ks < 4; ++ks) {
    bf16x8 b0 = Ble2[(ks * 4 + q) * 128 + (wave * 2 + 0) * 16 + nn];
    bf16x8 b1 = Ble2[(ks * 4 + q) * 128 + (wave * 2 + 1) * 16 + nn];
#pragma unroll
    for (int rg = 0; rg < 2; ++rg) {
      bf16x8 a = *(const bf16x8*)&As[(rg * 16 + nn) * AS_STRIDE + 128 + ks * 32 + q * 8];
      acc2[rg][0] = __builtin_amdgcn_mfma_f32_16x16x32_bf16(a, b0, acc2[rg][0], 0, 0, 0);
      acc2[rg][1] = __builtin_amdgcn_mfma_f32_16x16x32_bf16(a, b1, acc2[rg][1], 0, 0, 0);
    }
  }
  float yv[2][2][4];
  float psum[2][4]  = {{0,0,0,0},{0,0,0,0}};
  float psum2[2][4] = {{0,0,0,0},{0,0,0,0}};
  float pd2[2][4]   = {{0,0,0,0},{0,0,0,0}};
  float px2[2][4]   = {{0,0,0,0},{0,0,0,0}};
#pragma unroll
  for (int t2 = 0; t2 < 2; ++t2) {
    int col = (wave * 2 + t2) * 16 + nn;
    float bias = le_b2v[col];
#pragma unroll
    for (int rg = 0; rg < 2; ++rg)
#pragma unroll
      for (int r = 0; r < 4; ++r) {
        int p = rg * 16 + q * 4 + r;
        float d  = (acc2[rg][t2][r] + bias) * s_rv[p];
        float xv = b2f((unsigned short)As[p * AS_STRIDE + col]);
        float y  = xv + d;
        yv[rg][t2][r] = y;
        psum[rg][r]  += y;       psum2[rg][r] += y * y;
        pd2[rg][r]   += d * d;   px2[rg][r]   += xv * xv;
      }
  }
#pragma unroll
  for (int off = 1; off < 16; off <<= 1) {
#pragma unroll
    for (int rg = 0; rg < 2; ++rg)
#pragma unroll
      for (int r = 0; r < 4; ++r) {
        psum[rg][r]  += __shfl_xor(psum[rg][r], off);
        psum2[rg][r] += __shfl_xor(psum2[rg][r], off);
        pd2[rg][r]   += __shfl_xor(pd2[rg][r], off);
        px2[rg][r]   += __shfl_xor(px2[rg][r], off);
      }
  }
  if (nn == 0) {
#pragma unroll
    for (int rg = 0; rg < 2; ++rg)
#pragma unroll
      for (int r = 0; r < 4; ++r) {
        f32x4 st = { psum[rg][r], psum2[rg][r], pd2[rg][r], px2[rg][r] };
        *(f32x4*)&s_lnpart[wave][rg * 16 + q * 4 + r][0] = st;
      }
  }
  __syncthreads();
  {
    float gcol[2], bcol[2];
#pragma unroll
    for (int t2 = 0; t2 < 2; ++t2) {
      int col = (wave * 2 + t2) * 16 + nn;
      gcol[t2] = ln_gv[col]; bcol[t2] = ln_bv[col];
    }
#pragma unroll
    for (int rg = 0; rg < 2; ++rg)
#pragma unroll
      for (int r = 0; r < 4; ++r) {
        int p = rg * 16 + q * 4 + r;
        f32x4 s0 = *(const f32x4*)&s_lnpart[0][p][0];
        f32x4 s1 = *(const f32x4*)&s_lnpart[1][p][0];
        f32x4 s2 = *(const f32x4*)&s_lnpart[2][p][0];
        f32x4 s3 = *(const f32x4*)&s_lnpart[3][p][0];
        float sy  = s0[0] + s1[0] + s2[0] + s3[0];
        float sy2 = s0[1] + s1[1] + s2[1] + s3[1];
        float sd2 = s0[2] + s1[2] + s2[2] + s3[2];
        float sx2 = s0[3] + s1[3] + s2[3] + s3[3];
        float mu  = sy * (1.f / 128.f);
        float var = sy2 * (1.f / 128.f) - mu * mu;
        float inv = rsqrtf(var + 1e-5f);
        if (wave == 0 && nn == 0) {
          float gain = sqrtf(sd2) / (sqrtf(sx2) + 1e-6f);
          s_gain[p] = fminf(fmaxf(1.f - expf(-gain), 0.f), 1.f);
        }
        float* orow = out_fused + (size_t)(n0 + p) * C;
#pragma unroll
        for (int t2 = 0; t2 < 2; ++t2) {
          int col = (wave * 2 + t2) * 16 + nn;
          orow[col] = (yv[rg][t2][r] - mu) * inv * gcol[t2] + bcol[t2];
        }
      }
  }
  __syncthreads();

  // ================= P6: quality (N,11) =======================================
  for (int idx = tid; idx < PTILE * 11; idx += BLK) {
    int p2 = idx / 11, k = idx - p2 * 11;
    float v = 0.0f;
    if (k < 3)       v = s_route[p2][k];
    else if (k == 3) v = s_pfg[p2];
    else if (k == 4) v = s_rn[p2];
    else if (k == 5) v = s_valid[p2];
    else if (k == 7) v = s_gain[p2];
    v = fminf(fmaxf(v, 0.0f), 1.0f);
    out_qual[(size_t)(n0 + p2) * 11 + k] = v;
  }
}

} // namespace

extern "C" void kernel_launch(void* const* d_in, const int* in_sizes, int n_in,
                              void* d_out, int out_size, void* d_ws, size_t ws_size,
                              hipStream_t stream) {
  const float* x       = (const float*)d_in[0];
  const int*   indices = (const int*)d_in[1];
  const float* vox     = (const float*)d_in[2];
  const float* pcr     = (const float*)d_in[3];
  const float* trans   = (const float*)d_in[4];
  const float* imgf    = (const float*)d_in[5];
  const int*   imgh    = (const int*)d_in[6];
  const int*   imgw    = (const int*)d_in[7];
  const float* fg_w1   = (const float*)d_in[8];
  const float* fg_b1   = (const float*)d_in[9];
  const float* fg_w2   = (const float*)d_in[10];
  const float* fg_b2   = (const float*)d_in[11];
  const float* rt_w1   = (const float*)d_in[12];
  const float* rt_b1   = (const float*)d_in[13];
  const float* rt_w2   = (const float*)d_in[14];
  const float* rt_b2   = (const float*)d_in[15];
  const float* le_w1   = (const float*)d_in[16];
  const float* le_b1   = (const float*)d_in[17];
  const float* le_w2   = (const float*)d_in[18];
  const float* le_b2   = (const float*)d_in[19];
  const float* ln_g    = (const float*)d_in[20];
  const float* ln_b    = (const float*)d_in[21];

  short* wpack = (short*)d_ws;
  short* imgT  = (short*)((char*)d_ws + IMG_BYTE_OFF);

  float* out_fused = (float*)d_out;
  float* out_qual  = out_fused + (size_t)NPTS * C;

  (void)in_sizes; (void)n_in; (void)out_size; (void)ws_size;

  prep_kernel<<<IMG_BLOCKS + WP_BLOCKS, BLK, 0, stream>>>(
      imgf, le_w1, le_w2, fg_w1, rt_w1, wpack, imgT);
  fuse_kernel<<<NPTS / PTILE, BLK, 0, stream>>>(
      x, indices, vox, pcr, trans, imgh, imgw,
      fg_b1, fg_w2, fg_b2,
      rt_w1, rt_b1, rt_w2, rt_b2,
      le_b1, le_b2, ln_g, ln_b,
      wpack, imgT, out_fused, out_qual);
}

// Round 9
// 334.954 us; speedup vs baseline: 1.1112x; 1.1112x over previous
//
#include <hip/hip_runtime.h>

namespace {

typedef __attribute__((ext_vector_type(8))) short bf16x8;
typedef __attribute__((ext_vector_type(4))) float f32x4;

constexpr int C     = 128;
constexpr int HF    = 116;
constexpr int WF    = 200;
constexpr int PTILE = 32;
constexpr int BLK   = 256;
constexpr int NPTS  = 200000;
constexpr int AS_STRIDE  = 264;   // 256 + 8 shorts pad
constexpr int HID_STRIDE = 136;   // (prep LDS transpose stride)

// ws layout (short offsets): packed bf16 weights in B-frag order
constexpr int W_LE1 = 0;          // 256x128 -> 32768 shorts
constexpr int W_LE2 = 32768;      // 128x128 -> 16384
constexpr int W_FG  = 49152;      // 128x64  -> 8192
constexpr int W_RT  = 57344;      // 128x64  -> 8192 (rows 0..127 of rt_w1)
constexpr size_t IMG_BYTE_OFF = 131072;   // NHWC bf16 image, 23.76 MB

constexpr int IMG_BLOCKS = 4 * HF * 2;    // 928 half-row transpose blocks
constexpr int WP_BLOCKS  = 256;           // weight pack blocks

__device__ __forceinline__ float b2f(unsigned short u) {
  union { unsigned int i; float f; } v; v.i = ((unsigned int)u) << 16; return v.f;
}
__device__ __forceinline__ unsigned short f2b(float f) {
  union { float f; unsigned int i; } v; v.f = f;
  unsigned int i = v.i;
  return (unsigned short)((i + 0x7fffu + ((i >> 16) & 1u)) >> 16);
}
__device__ __forceinline__ void unp(unsigned int u, float& lo, float& hi) {
  union { unsigned int i; float f; } a, b;
  a.i = u << 16; b.i = u & 0xffff0000u; lo = a.f; hi = b.f;
}
// packed f32x2 -> bf16x2 (RNE), single HW instruction
__device__ __forceinline__ unsigned int packb(float a, float b) {
  unsigned int r;
  asm("v_cvt_pk_bf16_f32 %0, %1, %2" : "=v"(r) : "v"(a), "v"(b));
  return r;
}

// ---- fused prep: image NCHW f32 -> NHWC bf16 (vectorized) + weight pack ----
__global__ __launch_bounds__(BLK) void prep_kernel(
    const float* __restrict__ imgf,
    const float* __restrict__ le_w1, const float* __restrict__ le_w2,
    const float* __restrict__ fg_w1, const float* __restrict__ rt_w1,
    short* __restrict__ wpack, short* __restrict__ imgT) {
  __shared__ short buf[100 * HID_STRIDE];   // [x][c], 27.2 KB
  const int blk = blockIdx.x;
  if (blk < IMG_BLOCKS) {
    const int half = blk & 1, by = blk >> 1;
    const int b = by / HF, y = by - b * HF;
    const int x0 = half * 100;
    const float* s = imgf + (size_t)b * C * HF * WF + (size_t)y * WF + x0;
    for (int i = threadIdx.x; i < C * 25; i += BLK) {
      int c = i / 25, qx = i - c * 25;
      float4 v = *(const float4*)(s + (size_t)c * (HF * WF) + qx * 4);
      int xb = qx * 4;
      buf[(xb + 0) * HID_STRIDE + c] = (short)f2b(v.x);
      buf[(xb + 1) * HID_STRIDE + c] = (short)f2b(v.y);
      buf[(xb + 2) * HID_STRIDE + c] = (short)f2b(v.z);
      buf[(xb + 3) * HID_STRIDE + c] = (short)f2b(v.w);
    }
    __syncthreads();
    short* d = imgT + ((size_t)(b * HF + y) * WF + x0) * C;
    for (int i = threadIdx.x; i < 100 * 16; i += BLK) {
      int xx = i >> 4, c8 = (i & 15) << 3;
      *(uint4*)(d + (size_t)xx * C + c8) = *(const uint4*)&buf[xx * HID_STRIDE + c8];
    }
  } else {
    int idx = (blk - IMG_BLOCKS) * BLK + threadIdx.x;   // 0..65535
    if (idx < 32768) {                     // le_w1 (256,128)
      int k = idx >> 7, n = idx & 127;
      wpack[W_LE1 + (((k >> 3) * 128 + n) << 3) + (k & 7)] = (short)f2b(le_w1[idx]);
    } else if (idx < 49152) {              // le_w2 (128,128)
      int l = idx - 32768; int k = l >> 7, n = l & 127;
      wpack[W_LE2 + (((k >> 3) * 128 + n) << 3) + (k & 7)] = (short)f2b(le_w2[l]);
    } else if (idx < 57344) {              // fg_w1 (128,64)
      int l = idx - 49152; int k = l >> 6, n = l & 63;
      wpack[W_FG + (((k >> 3) * 64 + n) << 3) + (k & 7)] = (short)f2b(fg_w1[l]);
    } else {                               // rt_w1 rows 0..127 (of 131,64)
      int l = idx - 57344; int k = l >> 6, n = l & 63;
      wpack[W_RT + (((k >> 3) * 64 + n) << 3) + (k & 7)] = (short)f2b(rt_w1[k * 64 + n]);
    }
  }
}

// ---- main fused kernel ----
// R5 structure (best measured: 139us fuse, no spills) + le1 B-fragment dedup:
// P3 wave owns DISTINCT 32-col slice x all 32 rows (acc[2][2]=16 regs, same
// budget as R5's acc[4]); le1 B-reads 128->64KB/block. P5 kept at R5's 16-row
// epilogue shape (R8 proved widening it to 32 rows spills: yv+stats 48 live).
__global__ __launch_bounds__(BLK, 6) void fuse_kernel(
    const float* __restrict__ x,       // (N,128)
    const int*   __restrict__ indices, // (N,4)
    const float* __restrict__ vox, const float* __restrict__ pcr,
    const float* __restrict__ trans,
    const int* __restrict__ imgh_p, const int* __restrict__ imgw_p,
    const float* __restrict__ fg_b1v, const float* __restrict__ fg_w2v,
    const float* __restrict__ fg_b2v,
    const float* __restrict__ rt_w1f,  // raw f32 (need rows 128..130)
    const float* __restrict__ rt_b1v, const float* __restrict__ rt_w2v,
    const float* __restrict__ rt_b2v,
    const float* __restrict__ le_b1v, const float* __restrict__ le_b2v,
    const float* __restrict__ ln_gv, const float* __restrict__ ln_bv,
    const short* __restrict__ wpack,   // packed bf16 weights (ws)
    const short* __restrict__ imgT,    // NHWC bf16 (ws)
    float* __restrict__ out_fused, float* __restrict__ out_qual) {
  __shared__ short As[PTILE * AS_STRIDE];     // [p][k]: x | sampled->hidden
  __shared__ float s_rn[32], s_pfg[32], s_valid[32], s_px[32], s_py[32];
  __shared__ float s_gain[32], s_rv[32];
  __shared__ float s_route[32][3];
  __shared__ int   s_bat[32];
  __shared__ __align__(16) float s_lnpart[4][16][4];

  const int tid  = threadIdx.x;
  const int n0   = blockIdx.x * PTILE;
  const int wave = tid >> 6;
  const int lane = tid & 63;
  const int q    = lane >> 4;     // quad
  const int nn   = lane & 15;

  // ================= P0: stage x -> As bf16; geometry ==========
  {
    const float4* xsrc = (const float4*)(x + (size_t)n0 * C);
    for (int i = tid; i < PTILE * C / 4; i += BLK) {   // 1024 float4
      float4 v = xsrc[i];
      int p = i >> 5, c4 = (i & 31) * 4;
      uint2 sv = { packb(v.x, v.y), packb(v.z, v.w) };
      *(uint2*)&As[p * AS_STRIDE + c4] = sv;
    }
  }
  if (tid < PTILE) {
    int p = tid;
    int base = (n0 + p) * 4;
    int bi = indices[base + 0], zi = indices[base + 1];
    int yi = indices[base + 2], xi = indices[base + 3];
    float sp[3] = { (float)xi, (float)yi, (float)zi };
    float cen[3];
#pragma unroll
    for (int k = 0; k < 3; ++k) {
      float cvs = vox[k] * 8.0f;
      cen[k] = sp[k] * cvs + pcr[k] + cvs * 0.5f;
    }
    float rn = sqrtf(cen[0] * cen[0] + cen[1] * cen[1]) / 72.0f;
    rn = fminf(fmaxf(rn, 0.0f), 1.0f);
    float pt3[3];
#pragma unroll
    for (int r = 0; r < 3; ++r) {
      const float* row = trans + (bi * 3 + r) * 4;
      pt3[r] = row[0] * cen[0] + row[1] * cen[1] + row[2] * cen[2] + row[3];
    }
    float depth = pt3[2];
    float safe  = fmaxf(depth, 1e-5f);
    float uf = pt3[0] / safe * ((float)WF / (float)imgw_p[0]);
    float vf = pt3[1] / safe * ((float)HF / (float)imgh_p[0]);
    float un = 2.0f * (uf / (float)(WF - 1)) - 1.0f;
    float vn = 2.0f * (vf / (float)(HF - 1)) - 1.0f;
    bool valid = (depth > 1e-5f) && (fabsf(un) <= 1.0f) && (fabsf(vn) <= 1.0f);
    s_rn[p] = rn;
    s_valid[p] = valid ? 1.0f : 0.0f;
    s_bat[p] = bi;
    s_px[p] = (un + 1.0f) * 0.5f * (float)(WF - 1);
    s_py[p] = (vn + 1.0f) * 0.5f * (float)(HF - 1);
  }
  __syncthreads();

  // ================= P1: waves0,1 fg MFMA+epi ; waves2,3 rt x-part MFMA =======
  f32x4 accS[4];
#pragma unroll
  for (int t = 0; t < 4; ++t) accS[t] = (f32x4){0.f, 0.f, 0.f, 0.f};
  if (wave < 2) {
    const int p0 = wave * 16;
    const bf16x8* Bfg = (const bf16x8*)(wpack + W_FG);
#pragma unroll 2
    for (int ks = 0; ks < 4; ++ks) {
      bf16x8 a = *(const bf16x8*)&As[(p0 + nn) * AS_STRIDE + ks * 32 + q * 8];
#pragma unroll
      for (int t = 0; t < 4; ++t) {
        bf16x8 b = Bfg[(ks * 4 + q) * 64 + t * 16 + nn];
        accS[t] = __builtin_amdgcn_mfma_f32_16x16x32_bf16(a, b, accS[t], 0, 0, 0);
      }
    }
    float part[4] = {0.f, 0.f, 0.f, 0.f};
#pragma unroll
    for (int t = 0; t < 4; ++t) {
      int col = t * 16 + nn;
      float bias = fg_b1v[col];
      float wv2  = fg_w2v[col];
#pragma unroll
      for (int r = 0; r < 4; ++r)
        part[r] += fmaxf(accS[t][r] + bias, 0.f) * wv2;
    }
#pragma unroll
    for (int off = 1; off < 16; off <<= 1) {
#pragma unroll
      for (int r = 0; r < 4; ++r) part[r] += __shfl_xor(part[r], off);
    }
    if (nn == 0) {
      float b2 = fg_b2v[0];
#pragma unroll
      for (int r = 0; r < 4; ++r)
        s_pfg[p0 + q * 4 + r] = 1.f / (1.f + expf(-(part[r] + b2)));
    }
  } else {
    const int p0 = (wave - 2) * 16;
    const bf16x8* Brt = (const bf16x8*)(wpack + W_RT);
#pragma unroll 2
    for (int ks = 0; ks < 4; ++ks) {
      bf16x8 a = *(const bf16x8*)&As[(p0 + nn) * AS_STRIDE + ks * 32 + q * 8];
#pragma unroll
      for (int t = 0; t < 4; ++t) {
        bf16x8 b = Brt[(ks * 4 + q) * 64 + t * 16 + nn];
        accS[t] = __builtin_amdgcn_mfma_f32_16x16x32_bf16(a, b, accS[t], 0, 0, 0);
      }
    }
  }
  __syncthreads();

  // ====== P2: rt ext+epi (waves 2,3); sampling (all threads) ==================
  if (wave >= 2) {
    const int p0 = (wave - 2) * 16;
    float lg0[4] = {0,0,0,0}, lg1[4] = {0,0,0,0}, lg2[4] = {0,0,0,0};
#pragma unroll
    for (int t = 0; t < 4; ++t) {
      int col = t * 16 + nn;
      float b1 = rt_b1v[col];
      float wr = rt_w1f[128 * 64 + col];
      float wp = rt_w1f[129 * 64 + col];
      float wv = rt_w1f[130 * 64 + col];
      float w20 = rt_w2v[col * 3 + 0], w21 = rt_w2v[col * 3 + 1], w22 = rt_w2v[col * 3 + 2];
#pragma unroll
      for (int r = 0; r < 4; ++r) {
        int p = p0 + q * 4 + r;
        float h = accS[t][r] + b1 + s_rn[p] * wr + s_pfg[p] * wp + s_valid[p] * wv;
        h = fmaxf(h, 0.f);
        lg0[r] += h * w20; lg1[r] += h * w21; lg2[r] += h * w22;
      }
    }
#pragma unroll
    for (int off = 1; off < 16; off <<= 1) {
#pragma unroll
      for (int r = 0; r < 4; ++r) {
        lg0[r] += __shfl_xor(lg0[r], off);
        lg1[r] += __shfl_xor(lg1[r], off);
        lg2[r] += __shfl_xor(lg2[r], off);
      }
    }
    if (nn == 0) {
      float rb0 = rt_b2v[0], rb1 = rt_b2v[1], rb2 = rt_b2v[2];
#pragma unroll
      for (int r = 0; r < 4; ++r) {
        int p = p0 + q * 4 + r;
        float l0 = lg0[r] + rb0, l1 = lg1[r] + rb1, l2 = lg2[r] + rb2;
        float m = fmaxf(l0, fmaxf(l1, l2));
        float e0 = expf(l0 - m), e1 = expf(l1 - m), e2 = expf(l2 - m);
        float inv = 1.f / (e0 + e1 + e2);
        s_route[p][0] = e0 * inv; s_route[p][1] = e1 * inv; s_route[p][2] = e2 * inv;
        s_rv[p] = e1 * inv * s_valid[p];
      }
    }
  }
  // sampling (all threads): thread = (point, 16-ch group)
  {
    int p = tid >> 3, grp = tid & 7, ch0 = grp * 16;
    float sacc[16];
#pragma unroll
    for (int k = 0; k < 16; ++k) sacc[k] = 0.f;
    if (s_valid[p] > 0.5f) {
      float px = s_px[p], py = s_py[p];
      float x0f = floorf(px), y0f = floorf(py);
      float fx = px - x0f, fy = py - y0f;
      int ix = (int)x0f, iy = (int)y0f;
      int bb = s_bat[p];
#pragma unroll
      for (int dy = 0; dy < 2; ++dy) {
#pragma unroll
        for (int dx = 0; dx < 2; ++dx) {
          int xi = ix + dx, yi = iy + dy;
          if (xi >= 0 && xi < WF && yi >= 0 && yi < HF) {
            float w = (dx ? fx : 1.0f - fx) * (dy ? fy : 1.0f - fy);
            const short* tp = imgT + (((size_t)bb * HF + yi) * WF + xi) * C + ch0;
            uint4 u0 = *(const uint4*)tp;
            uint4 u1 = *(const uint4*)(tp + 8);
            float lo, hi;
            unp(u0.x, lo, hi); sacc[0] += w * lo;  sacc[1] += w * hi;
            unp(u0.y, lo, hi); sacc[2] += w * lo;  sacc[3] += w * hi;
            unp(u0.z, lo, hi); sacc[4] += w * lo;  sacc[5] += w * hi;
            unp(u0.w, lo, hi); sacc[6] += w * lo;  sacc[7] += w * hi;
            unp(u1.x, lo, hi); sacc[8] += w * lo;  sacc[9] += w * hi;
            unp(u1.y, lo, hi); sacc[10] += w * lo; sacc[11] += w * hi;
            unp(u1.z, lo, hi); sacc[12] += w * lo; sacc[13] += w * hi;
            unp(u1.w, lo, hi); sacc[14] += w * lo; sacc[15] += w * hi;
          }
        }
      }
    }
    uint4 o0 = { packb(sacc[0], sacc[1]),  packb(sacc[2], sacc[3]),
                 packb(sacc[4], sacc[5]),  packb(sacc[6], sacc[7]) };
    uint4 o1 = { packb(sacc[8], sacc[9]),  packb(sacc[10], sacc[11]),
                 packb(sacc[12], sacc[13]), packb(sacc[14], sacc[15]) };
    *(uint4*)&As[p * AS_STRIDE + 128 + ch0]     = o0;
    *(uint4*)&As[p * AS_STRIDE + 128 + ch0 + 8] = o1;
  }
  __syncthreads();

  // ====== P3: le1 MFMA K=256. Wave owns cols [wave*32, wave*32+32) x 32 rows ==
  // (le1 B-fragments deduplicated: 64KB/block instead of 128KB; acc 16 regs)
  {
    const bf16x8* Ble1 = (const bf16x8*)(wpack + W_LE1);
    f32x4 acc[2][2];   // [rg][t2]
#pragma unroll
    for (int rg = 0; rg < 2; ++rg)
#pragma unroll
      for (int t2 = 0; t2 < 2; ++t2) acc[rg][t2] = (f32x4){0.f, 0.f, 0.f, 0.f};
#pragma unroll 2
    for (int ks = 0; ks < 8; ++ks) {
      bf16x8 b0 = Ble1[(ks * 4 + q) * 128 + (wave * 2 + 0) * 16 + nn];
      bf16x8 b1 = Ble1[(ks * 4 + q) * 128 + (wave * 2 + 1) * 16 + nn];
#pragma unroll
      for (int rg = 0; rg < 2; ++rg) {
        bf16x8 a = *(const bf16x8*)&As[(rg * 16 + nn) * AS_STRIDE + ks * 32 + q * 8];
        acc[rg][0] = __builtin_amdgcn_mfma_f32_16x16x32_bf16(a, b0, acc[rg][0], 0, 0, 0);
        acc[rg][1] = __builtin_amdgcn_mfma_f32_16x16x32_bf16(a, b1, acc[rg][1], 0, 0, 0);
      }
    }
    // all waves done READING As[*][128..255]; overwrite with hidden bf16
    __syncthreads();
#pragma unroll
    for (int t2 = 0; t2 < 2; ++t2) {
      int col = (wave * 2 + t2) * 16 + nn;
      float bias = le_b1v[col];
#pragma unroll
      for (int rg = 0; rg < 2; ++rg)
#pragma unroll
        for (int r = 0; r < 4; ++r)
          As[(rg * 16 + q * 4 + r) * AS_STRIDE + 128 + col] =
              (short)f2b(fmaxf(acc[rg][t2][r] + bias, 0.f));
    }
    __syncthreads();
  }

  // ================= P5: le2 MFMA + delta/gain/layernorm (R5 shape) ===========
  const int pt = wave & 1, cg = wave >> 1;
  const int p0le = pt * 16;
  const bf16x8* Ble2 = (const bf16x8*)(wpack + W_LE2);
  f32x4 acc2[4];
#pragma unroll
  for (int t = 0; t < 4; ++t) acc2[t] = (f32x4){0.f, 0.f, 0.f, 0.f};
#pragma unroll 2
  for (int ks = 0; ks < 4; ++ks) {
    bf16x8 a = *(const bf16x8*)&As[(p0le + nn) * AS_STRIDE + 128 + ks * 32 + q * 8];
#pragma unroll
    for (int t = 0; t < 4; ++t) {
      bf16x8 b = Ble2[(ks * 4 + q) * 128 + (cg * 4 + t) * 16 + nn];
      acc2[t] = __builtin_amdgcn_mfma_f32_16x16x32_bf16(a, b, acc2[t], 0, 0, 0);
    }
  }
  float yv[4][4];
  float psum[4] = {0,0,0,0}, psum2[4] = {0,0,0,0}, pd2[4] = {0,0,0,0}, px2[4] = {0,0,0,0};
#pragma unroll
  for (int t = 0; t < 4; ++t) {
    int col = (cg * 4 + t) * 16 + nn;
    float bias = le_b2v[col];
#pragma unroll
    for (int r = 0; r < 4; ++r) {
      int p = p0le + q * 4 + r;
      float d  = (acc2[t][r] + bias) * s_rv[p];
      float xv = b2f((unsigned short)As[p * AS_STRIDE + col]);
      float y  = xv + d;
      yv[t][r] = y;
      psum[r]  += y;       psum2[r] += y * y;
      pd2[r]   += d * d;   px2[r]   += xv * xv;
    }
  }
#pragma unroll
  for (int off = 1; off < 16; off <<= 1) {
#pragma unroll
    for (int r = 0; r < 4; ++r) {
      psum[r]  += __shfl_xor(psum[r], off);
      psum2[r] += __shfl_xor(psum2[r], off);
      pd2[r]   += __shfl_xor(pd2[r], off);
      px2[r]   += __shfl_xor(px2[r], off);
    }
  }
  if (nn == 0) {
#pragma unroll
    for (int r = 0; r < 4; ++r) {
      f32x4 st = { psum[r], psum2[r], pd2[r], px2[r] };
      *(f32x4*)&s_lnpart[wave][q * 4 + r][0] = st;
    }
  }
  __syncthreads();
  {
    float gcol[4], bcol[4];
#pragma unroll
    for (int t = 0; t < 4; ++t) {
      int col = (cg * 4 + t) * 16 + nn;
      gcol[t] = ln_gv[col]; bcol[t] = ln_bv[col];
    }
#pragma unroll
    for (int r = 0; r < 4; ++r) {
      int lr = q * 4 + r;
      int p  = p0le + lr;
      f32x4 oth = *(const f32x4*)&s_lnpart[wave ^ 2][lr][0];
      float sy  = psum[r]  + oth[0];
      float sy2 = psum2[r] + oth[1];
      float sd2 = pd2[r]   + oth[2];
      float sx2 = px2[r]   + oth[3];
      float mu  = sy * (1.f / 128.f);
      float var = sy2 * (1.f / 128.f) - mu * mu;
      float inv = rsqrtf(var + 1e-5f);
      if (wave < 2 && nn == 0) {
        float gain = sqrtf(sd2) / (sqrtf(sx2) + 1e-6f);
        s_gain[p] = fminf(fmaxf(1.f - expf(-gain), 0.f), 1.f);
      }
      float* orow = out_fused + (size_t)(n0 + p) * C;
#pragma unroll
      for (int t = 0; t < 4; ++t) {
        int col = (cg * 4 + t) * 16 + nn;
        orow[col] = (yv[t][r] - mu) * inv * gcol[t] + bcol[t];
      }
    }
  }
  __syncthreads();

  // ================= P6: quality (N,11) =======================================
  for (int idx = tid; idx < PTILE * 11; idx += BLK) {
    int p2 = idx / 11, k = idx - p2 * 11;
    float v = 0.0f;
    if (k < 3)       v = s_route[p2][k];
    else if (k == 3) v = s_pfg[p2];
    else if (k == 4) v = s_rn[p2];
    else if (k == 5) v = s_valid[p2];
    else if (k == 7) v = s_gain[p2];
    v = fminf(fmaxf(v, 0.0f), 1.0f);
    out_qual[(size_t)(n0 + p2) * 11 + k] = v;
  }
}

} // namespace

extern "C" void kernel_launch(void* const* d_in, const int* in_sizes, int n_in,
                              void* d_out, int out_size, void* d_ws, size_t ws_size,
                              hipStream_t stream) {
  const float* x       = (const float*)d_in[0];
  const int*   indices = (const int*)d_in[1];
  const float* vox     = (const float*)d_in[2];
  const float* pcr     = (const float*)d_in[3];
  const float* trans   = (const float*)d_in[4];
  const float* imgf    = (const float*)d_in[5];
  const int*   imgh    = (const int*)d_in[6];
  const int*   imgw    = (const int*)d_in[7];
  const float* fg_w1   = (const float*)d_in[8];
  const float* fg_b1   = (const float*)d_in[9];
  const float* fg_w2   = (const float*)d_in[10];
  const float* fg_b2   = (const float*)d_in[11];
  const float* rt_w1   = (const float*)d_in[12];
  const float* rt_b1   = (const float*)d_in[13];
  const float* rt_w2   = (const float*)d_in[14];
  const float* rt_b2   = (const float*)d_in[15];
  const float* le_w1   = (const float*)d_in[16];
  const float* le_b1   = (const float*)d_in[17];
  const float* le_w2   = (const float*)d_in[18];
  const float* le_b2   = (const float*)d_in[19];
  const float* ln_g    = (const float*)d_in[20];
  const float* ln_b    = (const float*)d_in[21];

  short* wpack = (short*)d_ws;
  short* imgT  = (short*)((char*)d_ws + IMG_BYTE_OFF);

  float* out_fused = (float*)d_out;
  float* out_qual  = out_fused + (size_t)NPTS * C;

  (void)in_sizes; (void)n_in; (void)out_size; (void)ws_size;

  prep_kernel<<<IMG_BLOCKS + WP_BLOCKS, BLK, 0, stream>>>(
      imgf, le_w1, le_w2, fg_w1, rt_w1, wpack, imgT);
  fuse_kernel<<<NPTS / PTILE, BLK, 0, stream>>>(
      x, indices, vox, pcr, trans, imgh, imgw,
      fg_b1, fg_w2, fg_b2,
      rt_w1, rt_b1, rt_w2, rt_b2,
      le_b1, le_b2, ln_g, ln_b,
      wpack, imgT, out_fused, out_qual);
}

// Round 10
// 333.347 us; speedup vs baseline: 1.1165x; 1.0048x over previous
//
#include <hip/hip_runtime.h>

namespace {

typedef __attribute__((ext_vector_type(8))) short bf16x8;
typedef __attribute__((ext_vector_type(4))) float f32x4;

constexpr int C     = 128;
constexpr int HF    = 116;
constexpr int WF    = 200;
constexpr int PTILE = 64;         // 64 points per block, 8 waves
constexpr int BLK   = 512;
constexpr int NPTS  = 200000;
constexpr int AS_STRIDE  = 264;   // 256 + 8 shorts pad
constexpr int HID_STRIDE = 136;   // (prep LDS transpose stride)

// ws layout (short offsets): packed bf16 weights in B-frag order
constexpr int W_LE1 = 0;          // 256x128 -> 32768 shorts
constexpr int W_LE2 = 32768;      // 128x128 -> 16384
constexpr int W_FG  = 49152;      // 128x64  -> 8192
constexpr int W_RT  = 57344;      // 128x64  -> 8192 (rows 0..127 of rt_w1)
constexpr size_t IMG_BYTE_OFF = 131072;   // NHWC bf16 image, 23.76 MB

constexpr int PREP_BLK   = 256;
constexpr int IMG_BLOCKS = 4 * HF * 2;    // 928 half-row transpose blocks
constexpr int WP_BLOCKS  = 256;           // weight pack blocks

__device__ __forceinline__ float b2f(unsigned short u) {
  union { unsigned int i; float f; } v; v.i = ((unsigned int)u) << 16; return v.f;
}
__device__ __forceinline__ unsigned short f2b(float f) {
  union { float f; unsigned int i; } v; v.f = f;
  unsigned int i = v.i;
  return (unsigned short)((i + 0x7fffu + ((i >> 16) & 1u)) >> 16);
}
__device__ __forceinline__ void unp(unsigned int u, float& lo, float& hi) {
  union { unsigned int i; float f; } a, b;
  a.i = u << 16; b.i = u & 0xffff0000u; lo = a.f; hi = b.f;
}
// packed f32x2 -> bf16x2 (RNE), single HW instruction
__device__ __forceinline__ unsigned int packb(float a, float b) {
  unsigned int r;
  asm("v_cvt_pk_bf16_f32 %0, %1, %2" : "=v"(r) : "v"(a), "v"(b));
  return r;
}

// ---- fused prep: image NCHW f32 -> NHWC bf16 (vectorized) + weight pack ----
__global__ __launch_bounds__(PREP_BLK) void prep_kernel(
    const float* __restrict__ imgf,
    const float* __restrict__ le_w1, const float* __restrict__ le_w2,
    const float* __restrict__ fg_w1, const float* __restrict__ rt_w1,
    short* __restrict__ wpack, short* __restrict__ imgT) {
  __shared__ short buf[100 * HID_STRIDE];   // [x][c], 27.2 KB
  const int blk = blockIdx.x;
  if (blk < IMG_BLOCKS) {
    const int half = blk & 1, by = blk >> 1;
    const int b = by / HF, y = by - b * HF;
    const int x0 = half * 100;
    const float* s = imgf + (size_t)b * C * HF * WF + (size_t)y * WF + x0;
    for (int i = threadIdx.x; i < C * 25; i += PREP_BLK) {
      int c = i / 25, qx = i - c * 25;
      float4 v = *(const float4*)(s + (size_t)c * (HF * WF) + qx * 4);
      int xb = qx * 4;
      buf[(xb + 0) * HID_STRIDE + c] = (short)f2b(v.x);
      buf[(xb + 1) * HID_STRIDE + c] = (short)f2b(v.y);
      buf[(xb + 2) * HID_STRIDE + c] = (short)f2b(v.z);
      buf[(xb + 3) * HID_STRIDE + c] = (short)f2b(v.w);
    }
    __syncthreads();
    short* d = imgT + ((size_t)(b * HF + y) * WF + x0) * C;
    for (int i = threadIdx.x; i < 100 * 16; i += PREP_BLK) {
      int xx = i >> 4, c8 = (i & 15) << 3;
      *(uint4*)(d + (size_t)xx * C + c8) = *(const uint4*)&buf[xx * HID_STRIDE + c8];
    }
  } else {
    int idx = (blk - IMG_BLOCKS) * PREP_BLK + threadIdx.x;   // 0..65535
    if (idx < 32768) {                     // le_w1 (256,128)
      int k = idx >> 7, n = idx & 127;
      wpack[W_LE1 + (((k >> 3) * 128 + n) << 3) + (k & 7)] = (short)f2b(le_w1[idx]);
    } else if (idx < 49152) {              // le_w2 (128,128)
      int l = idx - 32768; int k = l >> 7, n = l & 127;
      wpack[W_LE2 + (((k >> 3) * 128 + n) << 3) + (k & 7)] = (short)f2b(le_w2[l]);
    } else if (idx < 57344) {              // fg_w1 (128,64)
      int l = idx - 49152; int k = l >> 6, n = l & 63;
      wpack[W_FG + (((k >> 3) * 64 + n) << 3) + (k & 7)] = (short)f2b(fg_w1[l]);
    } else {                               // rt_w1 rows 0..127 (of 131,64)
      int l = idx - 57344; int k = l >> 6, n = l & 63;
      wpack[W_RT + (((k >> 3) * 64 + n) << 3) + (k & 7)] = (short)f2b(rt_w1[k * 64 + n]);
    }
  }
}

// ---- main fused kernel ----
// PTILE=64 via 8 waves, keeping R5's proven per-wave shapes (acc <= 4 f32x4):
//   P1: 4 fg-waves + 4 rt-waves, 16 rows each (R5 roles x2)
//   P3: wave owns ONE 16-col tile x all 64 rows (acc[4]; 1 B-load : 4 MFMA)
//   P5: wave = (row-quarter, col-half); R5 epilogue shape; LN pairs wave^1
// Per-point barrier count halves vs R5 (7 per 64 pts vs 14). LDS 38.7 KB ->
// 4 blocks/CU x 8 waves = full occupancy. VGPR cap 64 (R5 shapes measured 36).
__global__ __launch_bounds__(BLK, 8) void fuse_kernel(
    const float* __restrict__ x,       // (N,128)
    const int*   __restrict__ indices, // (N,4)
    const float* __restrict__ vox, const float* __restrict__ pcr,
    const float* __restrict__ trans,
    const int* __restrict__ imgh_p, const int* __restrict__ imgw_p,
    const float* __restrict__ fg_b1v, const float* __restrict__ fg_w2v,
    const float* __restrict__ fg_b2v,
    const float* __restrict__ rt_w1f,  // raw f32 (need rows 128..130)
    const float* __restrict__ rt_b1v, const float* __restrict__ rt_w2v,
    const float* __restrict__ rt_b2v,
    const float* __restrict__ le_b1v, const float* __restrict__ le_b2v,
    const float* __restrict__ ln_gv, const float* __restrict__ ln_bv,
    const short* __restrict__ wpack,   // packed bf16 weights (ws)
    const short* __restrict__ imgT,    // NHWC bf16 (ws)
    float* __restrict__ out_fused, float* __restrict__ out_qual) {
  __shared__ short As[PTILE * AS_STRIDE];     // 33.8 KB: x | sampled->hidden
  __shared__ float s_rn[64], s_pfg[64], s_valid[64], s_px[64], s_py[64];
  __shared__ float s_gain[64], s_rv[64];
  __shared__ float s_route[64][3];
  __shared__ int   s_bat[64];
  __shared__ __align__(16) float s_lnpart[8][16][4];

  const int tid  = threadIdx.x;
  const int n0   = blockIdx.x * PTILE;
  const int wave = tid >> 6;      // 0..7
  const int lane = tid & 63;
  const int q    = lane >> 4;     // quad
  const int nn   = lane & 15;

  // ================= P0: stage x -> As bf16; geometry ==========
  {
    const float4* xsrc = (const float4*)(x + (size_t)n0 * C);
    for (int i = tid; i < PTILE * C / 4; i += BLK) {   // 2048 float4, 4 iters
      float4 v = xsrc[i];
      int p = i >> 5, c4 = (i & 31) * 4;
      uint2 sv = { packb(v.x, v.y), packb(v.z, v.w) };
      *(uint2*)&As[p * AS_STRIDE + c4] = sv;
    }
  }
  if (tid < PTILE) {
    int p = tid;
    int base = (n0 + p) * 4;
    int bi = indices[base + 0], zi = indices[base + 1];
    int yi = indices[base + 2], xi = indices[base + 3];
    float sp[3] = { (float)xi, (float)yi, (float)zi };
    float cen[3];
#pragma unroll
    for (int k = 0; k < 3; ++k) {
      float cvs = vox[k] * 8.0f;
      cen[k] = sp[k] * cvs + pcr[k] + cvs * 0.5f;
    }
    float rn = sqrtf(cen[0] * cen[0] + cen[1] * cen[1]) / 72.0f;
    rn = fminf(fmaxf(rn, 0.0f), 1.0f);
    float pt3[3];
#pragma unroll
    for (int r = 0; r < 3; ++r) {
      const float* row = trans + (bi * 3 + r) * 4;
      pt3[r] = row[0] * cen[0] + row[1] * cen[1] + row[2] * cen[2] + row[3];
    }
    float depth = pt3[2];
    float safe  = fmaxf(depth, 1e-5f);
    float uf = pt3[0] / safe * ((float)WF / (float)imgw_p[0]);
    float vf = pt3[1] / safe * ((float)HF / (float)imgh_p[0]);
    float un = 2.0f * (uf / (float)(WF - 1)) - 1.0f;
    float vn = 2.0f * (vf / (float)(HF - 1)) - 1.0f;
    bool valid = (depth > 1e-5f) && (fabsf(un) <= 1.0f) && (fabsf(vn) <= 1.0f);
    s_rn[p] = rn;
    s_valid[p] = valid ? 1.0f : 0.0f;
    s_bat[p] = bi;
    s_px[p] = (un + 1.0f) * 0.5f * (float)(WF - 1);
    s_py[p] = (vn + 1.0f) * 0.5f * (float)(HF - 1);
  }
  __syncthreads();

  // ========== P1: waves0-3 fg (16 rows each); waves4-7 rt (16 rows each) ======
  f32x4 accS[4];
#pragma unroll
  for (int t = 0; t < 4; ++t) accS[t] = (f32x4){0.f, 0.f, 0.f, 0.f};
  if (wave < 4) {
    const int p0 = wave * 16;
    const bf16x8* Bfg = (const bf16x8*)(wpack + W_FG);
#pragma unroll 2
    for (int ks = 0; ks < 4; ++ks) {
      bf16x8 a = *(const bf16x8*)&As[(p0 + nn) * AS_STRIDE + ks * 32 + q * 8];
#pragma unroll
      for (int t = 0; t < 4; ++t) {
        bf16x8 b = Bfg[(ks * 4 + q) * 64 + t * 16 + nn];
        accS[t] = __builtin_amdgcn_mfma_f32_16x16x32_bf16(a, b, accS[t], 0, 0, 0);
      }
    }
    float part[4] = {0.f, 0.f, 0.f, 0.f};
#pragma unroll
    for (int t = 0; t < 4; ++t) {
      int col = t * 16 + nn;
      float bias = fg_b1v[col];
      float wv2  = fg_w2v[col];
#pragma unroll
      for (int r = 0; r < 4; ++r)
        part[r] += fmaxf(accS[t][r] + bias, 0.f) * wv2;
    }
#pragma unroll
    for (int off = 1; off < 16; off <<= 1) {
#pragma unroll
      for (int r = 0; r < 4; ++r) part[r] += __shfl_xor(part[r], off);
    }
    if (nn == 0) {
      float b2 = fg_b2v[0];
#pragma unroll
      for (int r = 0; r < 4; ++r)
        s_pfg[p0 + q * 4 + r] = 1.f / (1.f + expf(-(part[r] + b2)));
    }
  } else {
    const int p0 = (wave - 4) * 16;
    const bf16x8* Brt = (const bf16x8*)(wpack + W_RT);
#pragma unroll 2
    for (int ks = 0; ks < 4; ++ks) {
      bf16x8 a = *(const bf16x8*)&As[(p0 + nn) * AS_STRIDE + ks * 32 + q * 8];
#pragma unroll
      for (int t = 0; t < 4; ++t) {
        bf16x8 b = Brt[(ks * 4 + q) * 64 + t * 16 + nn];
        accS[t] = __builtin_amdgcn_mfma_f32_16x16x32_bf16(a, b, accS[t], 0, 0, 0);
      }
    }
  }
  __syncthreads();

  // ====== P2: rt ext+epi (waves 4-7); sampling (all threads) ==================
  if (wave >= 4) {
    const int p0 = (wave - 4) * 16;
    float lg0[4] = {0,0,0,0}, lg1[4] = {0,0,0,0}, lg2[4] = {0,0,0,0};
#pragma unroll
    for (int t = 0; t < 4; ++t) {
      int col = t * 16 + nn;
      float b1 = rt_b1v[col];
      float wr = rt_w1f[128 * 64 + col];
      float wp = rt_w1f[129 * 64 + col];
      float wv = rt_w1f[130 * 64 + col];
      float w20 = rt_w2v[col * 3 + 0], w21 = rt_w2v[col * 3 + 1], w22 = rt_w2v[col * 3 + 2];
#pragma unroll
      for (int r = 0; r < 4; ++r) {
        int p = p0 + q * 4 + r;
        float h = accS[t][r] + b1 + s_rn[p] * wr + s_pfg[p] * wp + s_valid[p] * wv;
        h = fmaxf(h, 0.f);
        lg0[r] += h * w20; lg1[r] += h * w21; lg2[r] += h * w22;
      }
    }
#pragma unroll
    for (int off = 1; off < 16; off <<= 1) {
#pragma unroll
      for (int r = 0; r < 4; ++r) {
        lg0[r] += __shfl_xor(lg0[r], off);
        lg1[r] += __shfl_xor(lg1[r], off);
        lg2[r] += __shfl_xor(lg2[r], off);
      }
    }
    if (nn == 0) {
      float rb0 = rt_b2v[0], rb1 = rt_b2v[1], rb2 = rt_b2v[2];
#pragma unroll
      for (int r = 0; r < 4; ++r) {
        int p = p0 + q * 4 + r;
        float l0 = lg0[r] + rb0, l1 = lg1[r] + rb1, l2 = lg2[r] + rb2;
        float m = fmaxf(l0, fmaxf(l1, l2));
        float e0 = expf(l0 - m), e1 = expf(l1 - m), e2 = expf(l2 - m);
        float inv = 1.f / (e0 + e1 + e2);
        s_route[p][0] = e0 * inv; s_route[p][1] = e1 * inv; s_route[p][2] = e2 * inv;
        s_rv[p] = e1 * inv * s_valid[p];
      }
    }
  }
  // sampling (all threads): thread = (point, 16-ch group), p = 0..63
  {
    int p = tid >> 3, grp = tid & 7, ch0 = grp * 16;
    float sacc[16];
#pragma unroll
    for (int k = 0; k < 16; ++k) sacc[k] = 0.f;
    if (s_valid[p] > 0.5f) {
      float px = s_px[p], py = s_py[p];
      float x0f = floorf(px), y0f = floorf(py);
      float fx = px - x0f, fy = py - y0f;
      int ix = (int)x0f, iy = (int)y0f;
      int bb = s_bat[p];
#pragma unroll
      for (int dy = 0; dy < 2; ++dy) {
#pragma unroll
        for (int dx = 0; dx < 2; ++dx) {
          int xi = ix + dx, yi = iy + dy;
          if (xi >= 0 && xi < WF && yi >= 0 && yi < HF) {
            float w = (dx ? fx : 1.0f - fx) * (dy ? fy : 1.0f - fy);
            const short* tp = imgT + (((size_t)bb * HF + yi) * WF + xi) * C + ch0;
            uint4 u0 = *(const uint4*)tp;
            uint4 u1 = *(const uint4*)(tp + 8);
            float lo, hi;
            unp(u0.x, lo, hi); sacc[0] += w * lo;  sacc[1] += w * hi;
            unp(u0.y, lo, hi); sacc[2] += w * lo;  sacc[3] += w * hi;
            unp(u0.z, lo, hi); sacc[4] += w * lo;  sacc[5] += w * hi;
            unp(u0.w, lo, hi); sacc[6] += w * lo;  sacc[7] += w * hi;
            unp(u1.x, lo, hi); sacc[8] += w * lo;  sacc[9] += w * hi;
            unp(u1.y, lo, hi); sacc[10] += w * lo; sacc[11] += w * hi;
            unp(u1.z, lo, hi); sacc[12] += w * lo; sacc[13] += w * hi;
            unp(u1.w, lo, hi); sacc[14] += w * lo; sacc[15] += w * hi;
          }
        }
      }
    }
    uint4 o0 = { packb(sacc[0], sacc[1]),  packb(sacc[2], sacc[3]),
                 packb(sacc[4], sacc[5]),  packb(sacc[6], sacc[7]) };
    uint4 o1 = { packb(sacc[8], sacc[9]),  packb(sacc[10], sacc[11]),
                 packb(sacc[12], sacc[13]), packb(sacc[14], sacc[15]) };
    *(uint4*)&As[p * AS_STRIDE + 128 + ch0]     = o0;
    *(uint4*)&As[p * AS_STRIDE + 128 + ch0 + 8] = o1;
  }
  __syncthreads();

  // ====== P3: le1 MFMA K=256. Wave owns ONE 16-col tile x all 64 rows =========
  {
    const bf16x8* Ble1 = (const bf16x8*)(wpack + W_LE1);
    f32x4 acc[4];   // [rg], 16 regs
#pragma unroll
    for (int rg = 0; rg < 4; ++rg) acc[rg] = (f32x4){0.f, 0.f, 0.f, 0.f};
#pragma unroll 2
    for (int ks = 0; ks < 8; ++ks) {
      bf16x8 b = Ble1[(ks * 4 + q) * 128 + wave * 16 + nn];
#pragma unroll
      for (int rg = 0; rg < 4; ++rg) {
        bf16x8 a = *(const bf16x8*)&As[(rg * 16 + nn) * AS_STRIDE + ks * 32 + q * 8];
        acc[rg] = __builtin_amdgcn_mfma_f32_16x16x32_bf16(a, b, acc[rg], 0, 0, 0);
      }
    }
    // all waves done READING As[*][128..255]; overwrite with hidden bf16
    __syncthreads();
    {
      int col = wave * 16 + nn;
      float bias = le_b1v[col];
#pragma unroll
      for (int rg = 0; rg < 4; ++rg)
#pragma unroll
        for (int r = 0; r < 4; ++r)
          As[(rg * 16 + q * 4 + r) * AS_STRIDE + 128 + col] =
              (short)f2b(fmaxf(acc[rg][r] + bias, 0.f));
    }
    __syncthreads();
  }

  // ====== P5: le2 MFMA + delta/gain/layernorm. wave=(row-quarter, col-half) ===
  const int rq  = wave >> 1;        // 0..3 -> rows [rq*16, rq*16+16)
  const int chh = wave & 1;         // 0..1 -> cols [chh*64, chh*64+64)
  const int p0le = rq * 16;
  const bf16x8* Ble2 = (const bf16x8*)(wpack + W_LE2);
  f32x4 acc2[4];
#pragma unroll
  for (int t = 0; t < 4; ++t) acc2[t] = (f32x4){0.f, 0.f, 0.f, 0.f};
#pragma unroll 2
  for (int ks = 0; ks < 4; ++ks) {
    bf16x8 a = *(const bf16x8*)&As[(p0le + nn) * AS_STRIDE + 128 + ks * 32 + q * 8];
#pragma unroll
    for (int t = 0; t < 4; ++t) {
      bf16x8 b = Ble2[(ks * 4 + q) * 128 + (chh * 4 + t) * 16 + nn];
      acc2[t] = __builtin_amdgcn_mfma_f32_16x16x32_bf16(a, b, acc2[t], 0, 0, 0);
    }
  }
  float yv[4][4];
  float psum[4] = {0,0,0,0}, psum2[4] = {0,0,0,0}, pd2[4] = {0,0,0,0}, px2[4] = {0,0,0,0};
#pragma unroll
  for (int t = 0; t < 4; ++t) {
    int col = (chh * 4 + t) * 16 + nn;
    float bias = le_b2v[col];
#pragma unroll
    for (int r = 0; r < 4; ++r) {
      int p = p0le + q * 4 + r;
      float d  = (acc2[t][r] + bias) * s_rv[p];
      float xv = b2f((unsigned short)As[p * AS_STRIDE + col]);
      float y  = xv + d;
      yv[t][r] = y;
      psum[r]  += y;       psum2[r] += y * y;
      pd2[r]   += d * d;   px2[r]   += xv * xv;
    }
  }
#pragma unroll
  for (int off = 1; off < 16; off <<= 1) {
#pragma unroll
    for (int r = 0; r < 4; ++r) {
      psum[r]  += __shfl_xor(psum[r], off);
      psum2[r] += __shfl_xor(psum2[r], off);
      pd2[r]   += __shfl_xor(pd2[r], off);
      px2[r]   += __shfl_xor(px2[r], off);
    }
  }
  if (nn == 0) {
#pragma unroll
    for (int r = 0; r < 4; ++r) {
      f32x4 st = { psum[r], psum2[r], pd2[r], px2[r] };
      *(f32x4*)&s_lnpart[wave][q * 4 + r][0] = st;
    }
  }
  __syncthreads();
  {
    float gcol[4], bcol[4];
#pragma unroll
    for (int t = 0; t < 4; ++t) {
      int col = (chh * 4 + t) * 16 + nn;
      gcol[t] = ln_gv[col]; bcol[t] = ln_bv[col];
    }
#pragma unroll
    for (int r = 0; r < 4; ++r) {
      int lr = q * 4 + r;
      int p  = p0le + lr;
      f32x4 oth = *(const f32x4*)&s_lnpart[wave ^ 1][lr][0];   // other col-half
      float sy  = psum[r]  + oth[0];
      float sy2 = psum2[r] + oth[1];
      float sd2 = pd2[r]   + oth[2];
      float sx2 = px2[r]   + oth[3];
      float mu  = sy * (1.f / 128.f);
      float var = sy2 * (1.f / 128.f) - mu * mu;
      float inv = rsqrtf(var + 1e-5f);
      if (chh == 0 && nn == 0) {
        float gain = sqrtf(sd2) / (sqrtf(sx2) + 1e-6f);
        s_gain[p] = fminf(fmaxf(1.f - expf(-gain), 0.f), 1.f);
      }
      float* orow = out_fused + (size_t)(n0 + p) * C;
#pragma unroll
      for (int t = 0; t < 4; ++t) {
        int col = (chh * 4 + t) * 16 + nn;
        orow[col] = (yv[t][r] - mu) * inv * gcol[t] + bcol[t];
      }
    }
  }
  __syncthreads();

  // ================= P6: quality (N,11) =======================================
  for (int idx = tid; idx < PTILE * 11; idx += BLK) {
    int p2 = idx / 11, k = idx - p2 * 11;
    float v = 0.0f;
    if (k < 3)       v = s_route[p2][k];
    else if (k == 3) v = s_pfg[p2];
    else if (k == 4) v = s_rn[p2];
    else if (k == 5) v = s_valid[p2];
    else if (k == 7) v = s_gain[p2];
    v = fminf(fmaxf(v, 0.0f), 1.0f);
    out_qual[(size_t)(n0 + p2) * 11 + k] = v;
  }
}

} // namespace

extern "C" void kernel_launch(void* const* d_in, const int* in_sizes, int n_in,
                              void* d_out, int out_size, void* d_ws, size_t ws_size,
                              hipStream_t stream) {
  const float* x       = (const float*)d_in[0];
  const int*   indices = (const int*)d_in[1];
  const float* vox     = (const float*)d_in[2];
  const float* pcr     = (const float*)d_in[3];
  const float* trans   = (const float*)d_in[4];
  const float* imgf    = (const float*)d_in[5];
  const int*   imgh    = (const int*)d_in[6];
  const int*   imgw    = (const int*)d_in[7];
  const float* fg_w1   = (const float*)d_in[8];
  const float* fg_b1   = (const float*)d_in[9];
  const float* fg_w2   = (const float*)d_in[10];
  const float* fg_b2   = (const float*)d_in[11];
  const float* rt_w1   = (const float*)d_in[12];
  const float* rt_b1   = (const float*)d_in[13];
  const float* rt_w2   = (const float*)d_in[14];
  const float* rt_b2   = (const float*)d_in[15];
  const float* le_w1   = (const float*)d_in[16];
  const float* le_b1   = (const float*)d_in[17];
  const float* le_w2   = (const float*)d_in[18];
  const float* le_b2   = (const float*)d_in[19];
  const float* ln_g    = (const float*)d_in[20];
  const float* ln_b    = (const float*)d_in[21];

  short* wpack = (short*)d_ws;
  short* imgT  = (short*)((char*)d_ws + IMG_BYTE_OFF);

  float* out_fused = (float*)d_out;
  float* out_qual  = out_fused + (size_t)NPTS * C;

  (void)in_sizes; (void)n_in; (void)out_size; (void)ws_size;

  prep_kernel<<<IMG_BLOCKS + WP_BLOCKS, PREP_BLK, 0, stream>>>(
      imgf, le_w1, le_w2, fg_w1, rt_w1, wpack, imgT);
  fuse_kernel<<<NPTS / PTILE, BLK, 0, stream>>>(
      x, indices, vox, pcr, trans, imgh, imgw,
      fg_b1, fg_w2, fg_b2,
      rt_w1, rt_b1, rt_w2, rt_b2,
      le_b1, le_b2, ln_g, ln_b,
      wpack, imgT, out_fused, out_qual);
}